// Round 3
// baseline (280.779 us; speedup 1.0000x reference)
//
#include <hip/hip_runtime.h>
#include <hip/hip_bf16.h>

typedef unsigned int u32;
typedef unsigned short u16;

using bf16x8 = __attribute__((ext_vector_type(8))) short;
using f32x4  = __attribute__((ext_vector_type(4))) float;

// ---------------- workspace layout (bytes) ----------------
#define OFF_IN     0L        // Wt_in   [128][72]  bf16 = 18432
#define OFF_C      18432L    // Wt_c    [128][136] bf16 = 34816
#define OFF_B0     53248L    // Wt_b[8] [128][136] bf16 = 8*34816
#define OFF_SKIP   331776L   // Wt_skip [128][72]
#define OFF_SKIPC  350208L   // Wt_skipc[128][136]
#define OFF_VIEW   385024L   // Wt_view [128][40] = 10240
#define OFF_VIEWC  395264L   // Wt_viewc[128][136]
#define OFF_BIAS0  430080L   // f32[128] b_in+b_c
#define OFF_BIASSK 430592L   // f32[128] b_skip+b_skipc
#define OFF_BIASV  431104L   // f32[128] b_view+b_viewc

// ---------------- LDS layout (bytes) ----------------
#define LDS_X   0        // activations [256][136] bf16, stride 272B = 69632
#define LDS_W   69632    // weight double buffer: 2 x [128][<=136] = 2*34816
#define LDS_SP  139264   // sigma partials [256][2] f32 = 2048
#define LDS_RP  141312   // rgb partials [256][2][3] f32 = 6144
#define LDS_TOTAL 147456

__device__ __forceinline__ u16 f2bf(float x) {
  union { float f; u32 u; } un; un.f = x;
  u32 u = un.u;
  return (u16)((u + 0x7fffu + ((u >> 16) & 1u)) >> 16);
}
__device__ __forceinline__ u32 pack2(float a, float b) {
  return (u32)f2bf(a) | ((u32)f2bf(b) << 16);
}
__device__ __forceinline__ float sel3(float a, float b, float c, int i) {
  return i == 0 ? a : (i == 1 ? b : c);
}
__device__ __forceinline__ float enc_val3(float a, float b, float c, int e, int kreal) {
  if (e >= kreal) return 0.f;
  if (e < 3) return sel3(a, b, c, e);
  int t = e - 3;
  int l = t / 6;
  int rem = t - l * 6;
  int pi = rem >= 3 ? rem - 3 : rem;
  float x = sel3(a, b, c, pi) * (float)(1 << l);
  return rem < 3 ? __sinf(x) : __cosf(x);
}
__device__ __forceinline__ bf16x8 mk8(u32 a, u32 b, u32 c, u32 d) {
  union { u32 u[4]; bf16x8 v; } t; t.u[0] = a; t.u[1] = b; t.u[2] = c; t.u[3] = d;
  return t.v;
}

// ---------------- prep kernel (unchanged) ----------------
__global__ void prep_kernel(
    const float* __restrict__ Win, const float* __restrict__ Wc, const float* __restrict__ Wb,
    const float* __restrict__ Wskip, const float* __restrict__ Wskipc,
    const float* __restrict__ Wview, const float* __restrict__ Wviewc,
    const float* __restrict__ bin, const float* __restrict__ bc,
    const float* __restrict__ bskip, const float* __restrict__ bskipc,
    const float* __restrict__ bview, const float* __restrict__ bviewc,
    char* __restrict__ ws) {
  int i = blockIdx.x * 256 + threadIdx.x;
  if (i >= 215424) return;
  int r = i;
  const float* src; int kpad, kreal; long dstoff;
  if (r < 9216)                    { src = Win;    kpad = 72;  kreal = 63;  dstoff = OFF_IN; }
  else if ((r -= 9216) < 17408)    { src = Wc;     kpad = 136; kreal = 128; dstoff = OFF_C; }
  else if ((r -= 17408) < 139264)  { int b = r / 17408; r -= b * 17408;
                                     src = Wb + (long)b * 16384; kpad = 136; kreal = 128;
                                     dstoff = OFF_B0 + (long)b * 34816; }
  else if ((r -= 139264) < 9216)   { src = Wskip;  kpad = 72;  kreal = 63;  dstoff = OFF_SKIP; }
  else if ((r -= 9216) < 17408)    { src = Wskipc; kpad = 136; kreal = 128; dstoff = OFF_SKIPC; }
  else if ((r -= 17408) < 5120)    { src = Wview;  kpad = 40;  kreal = 27;  dstoff = OFF_VIEW; }
  else if ((r -= 5120) < 17408)    { src = Wviewc; kpad = 136; kreal = 128; dstoff = OFF_VIEWC; }
  else {
    r -= 17408;
    int which = r >> 7, n = r & 127;
    const float* A  = which == 0 ? bin : (which == 1 ? bskip : bview);
    const float* Bp = which == 0 ? bc  : (which == 1 ? bskipc : bviewc);
    long off = which == 0 ? OFF_BIAS0 : (which == 1 ? OFF_BIASSK : OFF_BIASV);
    *(float*)(ws + off + (long)n * 4) = A[n] + Bp[n];
    return;
  }
  int n = r / kpad, k = r - n * kpad;
  float v = (k < kreal) ? src[(long)k * 128 + n] : 0.f;
  *(u16*)(ws + dstoff + ((long)n * kpad + k) * 2) = f2bf(v);
}

// ---------------- staging macros (T14 async split: load early, write late) ----------------
#define STG_LD(off, bytes)                                                     \
  do {                                                                         \
    _Pragma("unroll") for (int k_ = 0; k_ < 5; ++k_) {                         \
      if (k_ * 512 * 16 < (bytes)) {                                           \
        int u_ = tid + k_ * 512;                                               \
        if ((long)u_ * 16 < (bytes))                                           \
          stg[k_] = *(const int4*)(ws + (off) + (long)u_ * 16);                \
      }                                                                        \
    }                                                                          \
  } while (0)

#define STG_WR(bytes, b)                                                       \
  do {                                                                         \
    _Pragma("unroll") for (int k_ = 0; k_ < 5; ++k_) {                         \
      if (k_ * 512 * 16 < (bytes)) {                                           \
        int u_ = tid + k_ * 512;                                               \
        if ((long)u_ * 16 < (bytes))                                           \
          *(int4*)(lds + LDS_W + (b) * 34816 + (long)u_ * 16) = stg[k_];       \
      }                                                                        \
    }                                                                          \
  } while (0)

#define STG_DIRECT(off, bytes, b)                                              \
  do {                                                                         \
    _Pragma("unroll") for (int k_ = 0; k_ < 5; ++k_) {                         \
      if (k_ * 512 * 16 < (bytes)) {                                           \
        int u_ = tid + k_ * 512;                                               \
        if ((long)u_ * 16 < (bytes))                                           \
          *(int4*)(lds + LDS_W + (b) * 34816 + (long)u_ * 16) =                \
              *(const int4*)(ws + (off) + (long)u_ * 16);                      \
      }                                                                        \
    }                                                                          \
  } while (0)

// ---------------- GEMM macros (swapped operands: D[lane&15] = point-row) ----------------
// acc[mi][j]: m = 64*wr+16*mi+li (lane li), n = 64*wc+16*j+4*h+rr (reg rr)
#define GEMM_X(WBASE, NKT)                                                     \
  do {                                                                         \
    _Pragma("unroll") for (int kt = 0; kt < (NKT); ++kt) {                     \
      bf16x8 xf[4];                                                            \
      _Pragma("unroll") for (int mi = 0; mi < 4; ++mi)                         \
        xf[mi] = *(const bf16x8*)(lds + LDS_X + (64*wr + 16*mi + li) * 272 + kt * 64 + h16); \
      _Pragma("unroll") for (int j = 0; j < 4; ++j) {                          \
        bf16x8 wf = *(const bf16x8*)(lds + (WBASE) + (64*wc + 16*j + li) * 272 + kt * 64 + h16); \
        _Pragma("unroll") for (int mi = 0; mi < 4; ++mi)                       \
          acc[mi][j] = __builtin_amdgcn_mfma_f32_16x16x32_bf16(wf, xf[mi], acc[mi][j], 0, 0, 0); \
      }                                                                        \
    }                                                                          \
  } while (0)

#define GEMM_E(WBASE, WSTR, NKT, EF)                                           \
  do {                                                                         \
    _Pragma("unroll") for (int kt = 0; kt < (NKT); ++kt) {                     \
      _Pragma("unroll") for (int j = 0; j < 4; ++j) {                          \
        bf16x8 wf = *(const bf16x8*)(lds + (WBASE) + (64*wc + 16*j + li) * (WSTR) + kt * 64 + h16); \
        _Pragma("unroll") for (int mi = 0; mi < 4; ++mi)                       \
          acc[mi][j] = __builtin_amdgcn_mfma_f32_16x16x32_bf16(wf, (EF)[mi][kt], acc[mi][j], 0, 0, 0); \
      }                                                                        \
    }                                                                          \
  } while (0)

#define ACC_SET(bptr)                                                          \
  do {                                                                         \
    _Pragma("unroll") for (int j = 0; j < 4; ++j) {                            \
      f32x4 b4_ = *(const f32x4*)((bptr) + 64*wc + 16*j + 4*h);                \
      _Pragma("unroll") for (int mi = 0; mi < 4; ++mi) acc[mi][j] = b4_;       \
    }                                                                          \
  } while (0)

#define ACC_ADD(bptr)                                                          \
  do {                                                                         \
    _Pragma("unroll") for (int j = 0; j < 4; ++j) {                            \
      f32x4 b4_ = *(const f32x4*)((bptr) + 64*wc + 16*j + 4*h);                \
      _Pragma("unroll") for (int mi = 0; mi < 4; ++mi) acc[mi][j] += b4_;      \
    }                                                                          \
  } while (0)

#define STORE_X()                                                              \
  do {                                                                         \
    _Pragma("unroll") for (int mi = 0; mi < 4; ++mi)                           \
    _Pragma("unroll") for (int j = 0; j < 4; ++j) {                            \
      f32x4 v_ = acc[mi][j];                                                   \
      uint2 t_;                                                                \
      t_.x = pack2(fmaxf(v_[0], 0.f), fmaxf(v_[1], 0.f));                      \
      t_.y = pack2(fmaxf(v_[2], 0.f), fmaxf(v_[3], 0.f));                      \
      *(uint2*)(lds + LDS_X + (64*wr + 16*mi + li) * 272 + (64*wc + 16*j + 4*h) * 2) = t_; \
    }                                                                          \
  } while (0)

#define APP_LOAD(c)                                                            \
  f32x4 af##c[4];                                                              \
  do {                                                                         \
    _Pragma("unroll") for (int i2 = 0; i2 < 4; ++i2) {                         \
      int f4i = (4*(c) + i2) * 512 + tid;                                      \
      int row = f4i >> 5, c4i = f4i & 31;                                      \
      af##c[i2] = *(const f32x4*)(condition + (size_t)(p0 + row) * 256 + (32 + c4i) * 4); \
    }                                                                          \
  } while (0)

#define APP_PACK(c)                                                            \
  do {                                                                         \
    _Pragma("unroll") for (int i2 = 0; i2 < 4; ++i2) {                         \
      int i_ = 4*(c) + i2;                                                     \
      appst[2*i_]   = pack2(af##c[i2][0], af##c[i2][1]);                       \
      appst[2*i_+1] = pack2(af##c[i2][2], af##c[i2][3]);                       \
    }                                                                          \
  } while (0)

// __launch_bounds__(512, 1): LDS (147 KB) limits us to 1 block/CU regardless;
// (512, 2) capped VGPRs at 128 and spilled ~109 MB/dispatch to scratch (R2
// WRITE_SIZE evidence). With min-waves=1 the allocator gets 256 VGPRs: no spill.
__global__ void __launch_bounds__(512, 1) nerf_main(
    const float* __restrict__ coords, const float* __restrict__ condition,
    const float* __restrict__ ray_dir, const float* __restrict__ noise,
    const float* __restrict__ b_blocks, const float* __restrict__ W_out,
    const float* __restrict__ b_out, const float* __restrict__ W_rgb,
    const float* __restrict__ b_rgb, const char* __restrict__ ws,
    float* __restrict__ out) {
  extern __shared__ __align__(16) char lds[];
  const int tid = threadIdx.x;
  const int lane = tid & 63;
  const int wv = tid >> 6;          // 8 waves
  const int wr = wv >> 1, wc = wv & 1;
  const int li = lane & 15, h = lane >> 4;
  const int h16 = h * 16;
  const int p0 = blockIdx.x * 256;

  int4 stg[5];
  f32x4 acc[4][4];

  // ==== prologue: issue cond_shape loads ====
  f32x4 sh[16];
#pragma unroll
  for (int i = 0; i < 16; ++i) {
    int f4i = i * 512 + tid;
    int row = f4i >> 5, c4i = f4i & 31;
    sh[i] = *(const f32x4*)(condition + (size_t)(p0 + row) * 256 + c4i * 4);
  }
  // enc fragments in registers: rows 64*wr+16*mi+li, k = 32*kt+8*h+e
  bf16x8 encf[4][2];
#pragma unroll
  for (int mi = 0; mi < 4; ++mi) {
    int r = 64 * wr + 16 * mi + li;
    const float* cp = coords + (size_t)(p0 + r) * 3;
    float c0 = cp[0], c1 = cp[1], c2 = cp[2];
#pragma unroll
    for (int kt = 0; kt < 2; ++kt) {
      u32 w[4];
#pragma unroll
      for (int e2 = 0; e2 < 4; ++e2) {
        int k0 = kt * 32 + h * 8 + e2 * 2;
        w[e2] = pack2(enc_val3(c0, c1, c2, k0, 63), enc_val3(c0, c1, c2, k0 + 1, 63));
      }
      encf[mi][kt] = mk8(w[0], w[1], w[2], w[3]);
    }
  }
  // stage Win -> buf0
  STG_DIRECT(OFF_IN, 18432, 0);
  // pack shape -> stash, write to X
  u32 stash[32];
#pragma unroll
  for (int i = 0; i < 16; ++i) {
    stash[2*i]   = pack2(sh[i][0], sh[i][1]);
    stash[2*i+1] = pack2(sh[i][2], sh[i][3]);
    int f4i = i * 512 + tid;
    int row = f4i >> 5, c4i = f4i & 31;
    uint2 t; t.x = stash[2*i]; t.y = stash[2*i+1];
    *(uint2*)(lds + LDS_X + row * 272 + c4i * 8) = t;
  }
  __syncthreads();

  // ==== P0: Win (buf0, stride 144, kt2, enc regs) ====
  STG_LD(OFF_C, 34816);
  ACC_SET((const float*)(ws + OFF_BIAS0));
  GEMM_E(LDS_W + 0 * 34816, 144, 2, encf);
  STG_WR(34816, 1);
  __syncthreads();

  // ==== P1: Wc (buf1, X=shape) ====
  STG_LD(OFF_B0 + 0L * 34816, 34816);
  GEMM_X(LDS_W + 1 * 34816, 4);
  STG_WR(34816, 0);
  __syncthreads();
  STORE_X();
  __syncthreads();

  // ==== P2-P5: Wb0..Wb3 ====
  // P2 (buf0)
  STG_LD(OFF_B0 + 1L * 34816, 34816);
  ACC_SET(b_blocks + 0 * 128);
  GEMM_X(LDS_W + 0 * 34816, 4);
  STG_WR(34816, 1);
  __syncthreads();
  STORE_X();
  __syncthreads();
  // P3 (buf1)
  STG_LD(OFF_B0 + 2L * 34816, 34816);
  ACC_SET(b_blocks + 1 * 128);
  GEMM_X(LDS_W + 1 * 34816, 4);
  STG_WR(34816, 0);
  __syncthreads();
  STORE_X();
  __syncthreads();
  // P4 (buf0)
  STG_LD(OFF_B0 + 3L * 34816, 34816);
  ACC_SET(b_blocks + 2 * 128);
  GEMM_X(LDS_W + 0 * 34816, 4);
  STG_WR(34816, 1);
  __syncthreads();
  STORE_X();
  __syncthreads();
  // P5 (buf1) — no store (skip gets added before relu)
  STG_LD(OFF_SKIP, 18432);
  ACC_SET(b_blocks + 3 * 128);
  GEMM_X(LDS_W + 1 * 34816, 4);
  STG_WR(18432, 0);
  __syncthreads();

  // ==== P6: Wskip (buf0, stride 144, kt2, enc regs); rewrite X = cond_shape ====
  STG_LD(OFF_SKIPC, 34816);
  ACC_ADD((const float*)(ws + OFF_BIASSK));
  GEMM_E(LDS_W + 0 * 34816, 144, 2, encf);
  STG_WR(34816, 1);
#pragma unroll
  for (int i = 0; i < 16; ++i) {
    int f4i = i * 512 + tid;
    int row = f4i >> 5, c4i = f4i & 31;
    uint2 t; t.x = stash[2*i]; t.y = stash[2*i+1];
    *(uint2*)(lds + LDS_X + row * 272 + c4i * 8) = t;
  }
  __syncthreads();

  // ==== P7: Wskipc (buf1, X=shape) ====
  STG_LD(OFF_B0 + 4L * 34816, 34816);
  GEMM_X(LDS_W + 1 * 34816, 4);
  STG_WR(34816, 0);
  __syncthreads();
  STORE_X();
  __syncthreads();

  u32 appst[32];
  // ==== P8: Wb4 (buf0) + app chunk0 ====
  STG_LD(OFF_B0 + 5L * 34816, 34816);
  APP_LOAD(0);
  ACC_SET(b_blocks + 4 * 128);
  GEMM_X(LDS_W + 0 * 34816, 4);
  STG_WR(34816, 1);
  APP_PACK(0);
  __syncthreads();
  STORE_X();
  __syncthreads();
  // ==== P9: Wb5 (buf1) + app chunk1 ====
  STG_LD(OFF_B0 + 6L * 34816, 34816);
  APP_LOAD(1);
  ACC_SET(b_blocks + 5 * 128);
  GEMM_X(LDS_W + 1 * 34816, 4);
  STG_WR(34816, 0);
  APP_PACK(1);
  __syncthreads();
  STORE_X();
  __syncthreads();
  // ==== P10: Wb6 (buf0) + app chunk2 + ray loads ====
  STG_LD(OFF_B0 + 7L * 34816, 34816);
  APP_LOAD(2);
  float ray0[4], ray1[4], ray2[4];
#pragma unroll
  for (int mi = 0; mi < 4; ++mi) {
    size_t base = (size_t)(p0 + 64 * wr + 16 * mi + li) * 3;
    ray0[mi] = ray_dir[base]; ray1[mi] = ray_dir[base + 1]; ray2[mi] = ray_dir[base + 2];
  }
  ACC_SET(b_blocks + 6 * 128);
  GEMM_X(LDS_W + 0 * 34816, 4);
  STG_WR(34816, 1);
  APP_PACK(2);
  __syncthreads();
  STORE_X();
  __syncthreads();
  // ==== P11: Wb7 (buf1) + app chunk3 + noise; sigma partials ====
  STG_LD(OFF_VIEW, 10240);
  APP_LOAD(3);
  float nz = 0.f;
  if (tid < 256) nz = noise[p0 + tid];
  ACC_SET(b_blocks + 7 * 128);
  GEMM_X(LDS_W + 1 * 34816, 4);
  STG_WR(10240, 0);
  APP_PACK(3);
  {
    f32x4 wo[4];
#pragma unroll
    for (int j = 0; j < 4; ++j) wo[j] = *(const f32x4*)(W_out + 64 * wc + 16 * j + 4 * h);
#pragma unroll
    for (int mi = 0; mi < 4; ++mi) {
      float s = 0.f;
#pragma unroll
      for (int j = 0; j < 4; ++j)
#pragma unroll
        for (int rr = 0; rr < 4; ++rr) s += fmaxf(acc[mi][j][rr], 0.f) * wo[j][rr];
      s += __shfl_xor(s, 16); s += __shfl_xor(s, 32);
      if (h == 0) *(float*)(lds + LDS_SP + ((64 * wr + 16 * mi + li) * 2 + wc) * 4) = s;
    }
  }
  __syncthreads();

  // ==== P12: Wview (buf0, stride 80, kt1, encv regs); rewrite X=app; sigma combine ====
  STG_LD(OFF_VIEWC, 34816);
  bf16x8 envf[4][1];
#pragma unroll
  for (int mi = 0; mi < 4; ++mi) {
    float r0 = ray0[mi], r1 = ray1[mi], r2 = ray2[mi];
    float inv = 1.f / sqrtf(r0 * r0 + r1 * r1 + r2 * r2);
    r0 *= inv; r1 *= inv; r2 *= inv;
    u32 w[4];
#pragma unroll
    for (int e2 = 0; e2 < 4; ++e2) {
      int k0 = h * 8 + e2 * 2;
      w[e2] = pack2(enc_val3(r0, r1, r2, k0, 27), enc_val3(r0, r1, r2, k0 + 1, 27));
    }
    envf[mi][0] = mk8(w[0], w[1], w[2], w[3]);
  }
  ACC_ADD((const float*)(ws + OFF_BIASV));
  GEMM_E(LDS_W + 0 * 34816, 80, 1, envf);
  STG_WR(34816, 1);
#pragma unroll
  for (int i = 0; i < 16; ++i) {
    int f4i = i * 512 + tid;
    int row = f4i >> 5, c4i = f4i & 31;
    uint2 t; t.x = appst[2*i]; t.y = appst[2*i+1];
    *(uint2*)(lds + LDS_X + row * 272 + c4i * 8) = t;
  }
  float sig = 0.f;
  if (tid < 256) {
    const float* sp = (const float*)(lds + LDS_SP);
    float s = sp[2 * tid] + sp[2 * tid + 1] + b_out[0] + nz;
    sig = fmaxf(s, 0.f);
  }
  __syncthreads();

  // ==== P13: Wviewc (buf1, X=app); rgb ====
  GEMM_X(LDS_W + 1 * 34816, 4);
  {
#pragma unroll
    for (int mi = 0; mi < 4; ++mi) {
      float s0 = 0.f, s1 = 0.f, s2 = 0.f;
#pragma unroll
      for (int j = 0; j < 4; ++j)
#pragma unroll
        for (int rr = 0; rr < 4; ++rr) {
          float v = fmaxf(acc[mi][j][rr], 0.f);
          int n = 64 * wc + 16 * j + 4 * h + rr;
          s0 += v * W_rgb[n * 3 + 0];
          s1 += v * W_rgb[n * 3 + 1];
          s2 += v * W_rgb[n * 3 + 2];
        }
      s0 += __shfl_xor(s0, 16); s0 += __shfl_xor(s0, 32);
      s1 += __shfl_xor(s1, 16); s1 += __shfl_xor(s1, 32);
      s2 += __shfl_xor(s2, 16); s2 += __shfl_xor(s2, 32);
      if (h == 0) {
        float* rp = (float*)(lds + LDS_RP);
        int m_ = 64 * wr + 16 * mi + li;
        rp[(m_ * 2 + wc) * 3 + 0] = s0;
        rp[(m_ * 2 + wc) * 3 + 1] = s1;
        rp[(m_ * 2 + wc) * 3 + 2] = s2;
      }
    }
  }
  __syncthreads();
  if (tid < 256) {
    const float* rp = (const float*)(lds + LDS_RP);
    f32x4 o4;
    o4[0] = sig;
#pragma unroll
    for (int c = 0; c < 3; ++c) {
      float v = rp[(2 * tid) * 3 + c] + rp[(2 * tid + 1) * 3 + c] + b_rgb[c];
      o4[1 + c] = 1.f / (1.f + __expf(-v));
    }
    *(f32x4*)(out + (size_t)(p0 + tid) * 4) = o4;
  }
}

extern "C" void kernel_launch(void* const* d_in, const int* in_sizes, int n_in,
                              void* d_out, int out_size, void* d_ws, size_t ws_size,
                              hipStream_t stream) {
  const float* coords    = (const float*)d_in[0];
  const float* condition = (const float*)d_in[1];
  const float* ray_dir   = (const float*)d_in[2];
  const float* noise     = (const float*)d_in[3];
  const float* W_in      = (const float*)d_in[4];
  const float* b_in      = (const float*)d_in[5];
  const float* W_blocks  = (const float*)d_in[6];
  const float* b_blocks  = (const float*)d_in[7];
  const float* W_c       = (const float*)d_in[8];
  const float* b_c       = (const float*)d_in[9];
  const float* W_skip    = (const float*)d_in[10];
  const float* b_skip    = (const float*)d_in[11];
  const float* W_skipc   = (const float*)d_in[12];
  const float* b_skipc   = (const float*)d_in[13];
  const float* W_out     = (const float*)d_in[14];
  const float* b_out     = (const float*)d_in[15];
  const float* W_viewc   = (const float*)d_in[16];
  const float* b_viewc   = (const float*)d_in[17];
  const float* W_view    = (const float*)d_in[18];
  const float* b_view    = (const float*)d_in[19];
  const float* W_rgb     = (const float*)d_in[20];
  const float* b_rgb     = (const float*)d_in[21];
  char* ws = (char*)d_ws;
  float* out = (float*)d_out;

  prep_kernel<<<842, 256, 0, stream>>>(W_in, W_c, W_blocks, W_skip, W_skipc, W_view, W_viewc,
                                       b_in, b_c, b_skip, b_skipc, b_view, b_viewc, ws);
  nerf_main<<<1024, 512, LDS_TOTAL, stream>>>(coords, condition, ray_dir, noise,
                                              b_blocks, W_out, b_out, W_rgb, b_rgb, ws, out);
}

// Round 4
// 236.154 us; speedup vs baseline: 1.1890x; 1.1890x over previous
//
#include <hip/hip_runtime.h>
#include <hip/hip_bf16.h>

typedef unsigned int u32;
typedef unsigned short u16;

using bf16x8 = __attribute__((ext_vector_type(8))) short;
using f32x4  = __attribute__((ext_vector_type(4))) float;

// ---------------- workspace layout (bytes) ----------------
#define OFF_IN     0L        // Wt_in   [128][72]  bf16 = 18432
#define OFF_C      18432L    // Wt_c    [128][136] bf16 = 34816
#define OFF_B0     53248L    // Wt_b[8] [128][136] bf16 = 8*34816
#define OFF_SKIP   331776L   // Wt_skip [128][72]
#define OFF_SKIPC  350208L   // Wt_skipc[128][136]
#define OFF_VIEW   385024L   // Wt_view [128][40] = 10240
#define OFF_VIEWC  395264L   // Wt_viewc[128][136]
#define OFF_BIAS0  430080L   // f32[128] b_in+b_c
#define OFF_BIASSK 430592L   // f32[128] b_skip+b_skipc
#define OFF_BIASV  431104L   // f32[128] b_view+b_viewc

// ---------------- LDS layout (bytes) ----------------
#define LDS_X   0        // activations / cond halves [256][136] bf16, stride 272B = 69632
#define LDS_W   69632    // weight double buffer: 2 x 34816
#define LDS_SP  139264   // sigma partials [256][2] f32 = 2048
#define LDS_RP  141312   // rgb partials [256][2][3] f32 = 6144
#define LDS_TOTAL 147456

__device__ __forceinline__ u16 f2bf(float x) {
  union { float f; u32 u; } un; un.f = x;
  u32 u = un.u;
  return (u16)((u + 0x7fffu + ((u >> 16) & 1u)) >> 16);
}
__device__ __forceinline__ u32 pack2(float a, float b) {
  return (u32)f2bf(a) | ((u32)f2bf(b) << 16);
}
__device__ __forceinline__ float sel3(float a, float b, float c, int i) {
  return i == 0 ? a : (i == 1 ? b : c);
}
__device__ __forceinline__ float enc_val3(float a, float b, float c, int e, int kreal) {
  if (e >= kreal) return 0.f;
  if (e < 3) return sel3(a, b, c, e);
  int t = e - 3;
  int l = t / 6;
  int rem = t - l * 6;
  int pi = rem >= 3 ? rem - 3 : rem;
  float x = sel3(a, b, c, pi) * (float)(1 << l);
  return rem < 3 ? __sinf(x) : __cosf(x);
}
__device__ __forceinline__ bf16x8 mk8(u32 a, u32 b, u32 c, u32 d) {
  union { u32 u[4]; bf16x8 v; } t; t.u[0] = a; t.u[1] = b; t.u[2] = c; t.u[3] = d;
  return t.v;
}
// zero-VGPR weight staging: global -> LDS DMA (linear dest = wave base + lane*16)
__device__ __forceinline__ void gll16(const void* g, void* l) {
  __builtin_amdgcn_global_load_lds(
      (const __attribute__((address_space(1))) void*)g,
      (__attribute__((address_space(3))) void*)l, 16, 0, 0);
}

// ---------------- prep kernel (unchanged) ----------------
__global__ void prep_kernel(
    const float* __restrict__ Win, const float* __restrict__ Wc, const float* __restrict__ Wb,
    const float* __restrict__ Wskip, const float* __restrict__ Wskipc,
    const float* __restrict__ Wview, const float* __restrict__ Wviewc,
    const float* __restrict__ bin, const float* __restrict__ bc,
    const float* __restrict__ bskip, const float* __restrict__ bskipc,
    const float* __restrict__ bview, const float* __restrict__ bviewc,
    char* __restrict__ ws) {
  int i = blockIdx.x * 256 + threadIdx.x;
  if (i >= 215424) return;
  int r = i;
  const float* src; int kpad, kreal; long dstoff;
  if (r < 9216)                    { src = Win;    kpad = 72;  kreal = 63;  dstoff = OFF_IN; }
  else if ((r -= 9216) < 17408)    { src = Wc;     kpad = 136; kreal = 128; dstoff = OFF_C; }
  else if ((r -= 17408) < 139264)  { int b = r / 17408; r -= b * 17408;
                                     src = Wb + (long)b * 16384; kpad = 136; kreal = 128;
                                     dstoff = OFF_B0 + (long)b * 34816; }
  else if ((r -= 139264) < 9216)   { src = Wskip;  kpad = 72;  kreal = 63;  dstoff = OFF_SKIP; }
  else if ((r -= 9216) < 17408)    { src = Wskipc; kpad = 136; kreal = 128; dstoff = OFF_SKIPC; }
  else if ((r -= 17408) < 5120)    { src = Wview;  kpad = 40;  kreal = 27;  dstoff = OFF_VIEW; }
  else if ((r -= 5120) < 17408)    { src = Wviewc; kpad = 136; kreal = 128; dstoff = OFF_VIEWC; }
  else {
    r -= 17408;
    int which = r >> 7, n = r & 127;
    const float* A  = which == 0 ? bin : (which == 1 ? bskip : bview);
    const float* Bp = which == 0 ? bc  : (which == 1 ? bskipc : bviewc);
    long off = which == 0 ? OFF_BIAS0 : (which == 1 ? OFF_BIASSK : OFF_BIASV);
    *(float*)(ws + off + (long)n * 4) = A[n] + Bp[n];
    return;
  }
  int n = r / kpad, k = r - n * kpad;
  float v = (k < kreal) ? src[(long)k * 128 + n] : 0.f;
  *(u16*)(ws + dstoff + ((long)n * kpad + k) * 2) = f2bf(v);
}

// ---------------- staging: global_load_lds double buffer ----------------
#define GLL_W(off, bytes, b)                                                   \
  do {                                                                         \
    _Pragma("unroll") for (int it_ = 0; it_ < 5; ++it_) {                      \
      int o_ = it_ * 8192 + wv * 1024;                                         \
      if (o_ < (bytes))                                                        \
        gll16(ws + (off) + o_ + lane * 16, lds + LDS_W + (b) * 34816 + o_);    \
    }                                                                          \
  } while (0)

// stream one 128-col half of condition (f32) -> packed bf16 LDS_X
#define STREAM_COND(halfsel)                                                   \
  do {                                                                         \
    _Pragma("unroll") for (int c_ = 0; c_ < 4; ++c_) {                         \
      f32x4 v_[4];                                                             \
      _Pragma("unroll") for (int i2 = 0; i2 < 4; ++i2) {                       \
        int f4i = (4 * c_ + i2) * 512 + tid;                                   \
        int row = f4i >> 5, c4 = f4i & 31;                                     \
        v_[i2] = *(const f32x4*)(condition + (size_t)(p0 + row) * 256 +        \
                                 ((halfsel) * 32 + c4) * 4);                   \
      }                                                                        \
      _Pragma("unroll") for (int i2 = 0; i2 < 4; ++i2) {                       \
        int f4i = (4 * c_ + i2) * 512 + tid;                                   \
        int row = f4i >> 5, c4 = f4i & 31;                                     \
        uint2 t_; t_.x = pack2(v_[i2][0], v_[i2][1]);                          \
        t_.y = pack2(v_[i2][2], v_[i2][3]);                                    \
        *(uint2*)(lds + LDS_X + row * 272 + c4 * 8) = t_;                      \
      }                                                                        \
    }                                                                          \
  } while (0)

// recompute positional-encoding fragments from kept coords (12 regs)
#define ENC_COMPUTE(EF)                                                        \
  do {                                                                         \
    _Pragma("unroll") for (int mi_ = 0; mi_ < 4; ++mi_) {                      \
      _Pragma("unroll") for (int kt_ = 0; kt_ < 2; ++kt_) {                    \
        u32 w_[4];                                                             \
        _Pragma("unroll") for (int e2_ = 0; e2_ < 4; ++e2_) {                  \
          int k0_ = kt_ * 32 + h * 8 + e2_ * 2;                                \
          w_[e2_] = pack2(enc_val3(cx[mi_], cy[mi_], cz[mi_], k0_, 63),        \
                          enc_val3(cx[mi_], cy[mi_], cz[mi_], k0_ + 1, 63));   \
        }                                                                      \
        EF[mi_][kt_] = mk8(w_[0], w_[1], w_[2], w_[3]);                        \
      }                                                                        \
    }                                                                          \
  } while (0)

// ---------------- GEMM macros (swapped operands: D[lane&15] = point-row) ----------------
// acc[mi][j]: m = 64*wr+16*mi+li (lane li), n = 64*wc+16*j+4*h+rr (reg rr)
#define GEMM_X(WBASE, NKT)                                                     \
  do {                                                                         \
    _Pragma("unroll") for (int kt = 0; kt < (NKT); ++kt) {                     \
      bf16x8 xf[4];                                                            \
      _Pragma("unroll") for (int mi = 0; mi < 4; ++mi)                         \
        xf[mi] = *(const bf16x8*)(lds + LDS_X + (64*wr + 16*mi + li) * 272 + kt * 64 + h16); \
      _Pragma("unroll") for (int j = 0; j < 4; ++j) {                          \
        bf16x8 wf = *(const bf16x8*)(lds + (WBASE) + (64*wc + 16*j + li) * 272 + kt * 64 + h16); \
        _Pragma("unroll") for (int mi = 0; mi < 4; ++mi)                       \
          acc[mi][j] = __builtin_amdgcn_mfma_f32_16x16x32_bf16(wf, xf[mi], acc[mi][j], 0, 0, 0); \
      }                                                                        \
    }                                                                          \
  } while (0)

#define GEMM_E(WBASE, WSTR, NKT, EF)                                           \
  do {                                                                         \
    _Pragma("unroll") for (int kt = 0; kt < (NKT); ++kt) {                     \
      _Pragma("unroll") for (int j = 0; j < 4; ++j) {                          \
        bf16x8 wf = *(const bf16x8*)(lds + (WBASE) + (64*wc + 16*j + li) * (WSTR) + kt * 64 + h16); \
        _Pragma("unroll") for (int mi = 0; mi < 4; ++mi)                       \
          acc[mi][j] = __builtin_amdgcn_mfma_f32_16x16x32_bf16(wf, (EF)[mi][kt], acc[mi][j], 0, 0, 0); \
      }                                                                        \
    }                                                                          \
  } while (0)

#define ACC_SET(bptr)                                                          \
  do {                                                                         \
    _Pragma("unroll") for (int j = 0; j < 4; ++j) {                            \
      f32x4 b4_ = *(const f32x4*)((bptr) + 64*wc + 16*j + 4*h);                \
      _Pragma("unroll") for (int mi = 0; mi < 4; ++mi) acc[mi][j] = b4_;       \
    }                                                                          \
  } while (0)

#define ACC_ADD(bptr)                                                          \
  do {                                                                         \
    _Pragma("unroll") for (int j = 0; j < 4; ++j) {                            \
      f32x4 b4_ = *(const f32x4*)((bptr) + 64*wc + 16*j + 4*h);                \
      _Pragma("unroll") for (int mi = 0; mi < 4; ++mi) acc[mi][j] += b4_;      \
    }                                                                          \
  } while (0)

#define STORE_X()                                                              \
  do {                                                                         \
    _Pragma("unroll") for (int mi = 0; mi < 4; ++mi)                           \
    _Pragma("unroll") for (int j = 0; j < 4; ++j) {                            \
      f32x4 v_ = acc[mi][j];                                                   \
      uint2 t_;                                                                \
      t_.x = pack2(fmaxf(v_[0], 0.f), fmaxf(v_[1], 0.f));                      \
      t_.y = pack2(fmaxf(v_[2], 0.f), fmaxf(v_[3], 0.f));                      \
      *(uint2*)(lds + LDS_X + (64*wr + 16*mi + li) * 272 + (64*wc + 16*j + 4*h) * 2) = t_; \
    }                                                                          \
  } while (0)

// 512-thread blocks: compiler caps at 128 VGPR/wave (R2/R3 evidence).
// Kernel is designed to live under that: acc 64 + coords 12 + misc ~25.
__global__ void __launch_bounds__(512, 1) nerf_main(
    const float* __restrict__ coords, const float* __restrict__ condition,
    const float* __restrict__ ray_dir, const float* __restrict__ noise,
    const float* __restrict__ b_blocks, const float* __restrict__ W_out,
    const float* __restrict__ b_out, const float* __restrict__ W_rgb,
    const float* __restrict__ b_rgb, const char* __restrict__ ws,
    float* __restrict__ out) {
  extern __shared__ __align__(16) char lds[];
  const int tid = threadIdx.x;
  const int lane = tid & 63;
  const int wv = tid >> 6;          // 8 waves
  const int wr = wv >> 1, wc = wv & 1;
  const int li = lane & 15, h = lane >> 4;
  const int h16 = h * 16;
  const int p0 = blockIdx.x * 256;

  f32x4 acc[4][4];

  // ==== prologue: shape -> LDS_X, Win -> buf0, coords -> regs ====
  STREAM_COND(0);
  GLL_W(OFF_IN, 18432, 0);
  float cx[4], cy[4], cz[4];
#pragma unroll
  for (int mi = 0; mi < 4; ++mi) {
    const float* cp = coords + (size_t)(p0 + 64 * wr + 16 * mi + li) * 3;
    cx[mi] = cp[0]; cy[mi] = cp[1]; cz[mi] = cp[2];
  }
  __syncthreads();

  // ==== P0: enc@Win (buf0, stride 144) ====
  GLL_W(OFF_C, 34816, 1);
  {
    bf16x8 encf[4][2];
    ENC_COMPUTE(encf);
    ACC_SET((const float*)(ws + OFF_BIAS0));
    GEMM_E(LDS_W + 0 * 34816, 144, 2, encf);
  }
  __syncthreads();

  // ==== P1: shape@Wc (buf1) ====
  GLL_W(OFF_B0 + 0L * 34816, 34816, 0);
  GEMM_X(LDS_W + 1 * 34816, 4);
  __syncthreads();
  STORE_X();
  __syncthreads();

  // ==== P2-P5: Wb0..Wb3 ====
  GLL_W(OFF_B0 + 1L * 34816, 34816, 1);
  ACC_SET(b_blocks + 0 * 128);
  GEMM_X(LDS_W + 0 * 34816, 4);
  __syncthreads();
  STORE_X();
  __syncthreads();

  GLL_W(OFF_B0 + 2L * 34816, 34816, 0);
  ACC_SET(b_blocks + 1 * 128);
  GEMM_X(LDS_W + 1 * 34816, 4);
  __syncthreads();
  STORE_X();
  __syncthreads();

  GLL_W(OFF_B0 + 3L * 34816, 34816, 1);
  ACC_SET(b_blocks + 2 * 128);
  GEMM_X(LDS_W + 0 * 34816, 4);
  __syncthreads();
  STORE_X();
  __syncthreads();

  // P5 (buf1) — no store (skip added onto net4 pre-relu)
  GLL_W(OFF_SKIP, 18432, 0);
  ACC_SET(b_blocks + 3 * 128);
  GEMM_X(LDS_W + 1 * 34816, 4);
  __syncthreads();

  // ==== P6: enc@Wskip (buf0, stride 144); re-stream shape -> X ====
  GLL_W(OFF_SKIPC, 34816, 1);
  STREAM_COND(0);
  {
    bf16x8 encf[4][2];
    ENC_COMPUTE(encf);
    ACC_ADD((const float*)(ws + OFF_BIASSK));
    GEMM_E(LDS_W + 0 * 34816, 144, 2, encf);
  }
  __syncthreads();

  // ==== P7: shape@Wskipc (buf1) ====
  GLL_W(OFF_B0 + 4L * 34816, 34816, 0);
  GEMM_X(LDS_W + 1 * 34816, 4);
  __syncthreads();
  STORE_X();
  __syncthreads();

  // ==== P8-P10: Wb4..Wb6 ====
  GLL_W(OFF_B0 + 5L * 34816, 34816, 1);
  ACC_SET(b_blocks + 4 * 128);
  GEMM_X(LDS_W + 0 * 34816, 4);
  __syncthreads();
  STORE_X();
  __syncthreads();

  GLL_W(OFF_B0 + 6L * 34816, 34816, 0);
  ACC_SET(b_blocks + 5 * 128);
  GEMM_X(LDS_W + 1 * 34816, 4);
  __syncthreads();
  STORE_X();
  __syncthreads();

  GLL_W(OFF_B0 + 7L * 34816, 34816, 1);
  float ray0[4], ray1[4], ray2[4];
#pragma unroll
  for (int mi = 0; mi < 4; ++mi) {
    size_t base = (size_t)(p0 + 64 * wr + 16 * mi + li) * 3;
    ray0[mi] = ray_dir[base]; ray1[mi] = ray_dir[base + 1]; ray2[mi] = ray_dir[base + 2];
  }
  ACC_SET(b_blocks + 6 * 128);
  GEMM_X(LDS_W + 0 * 34816, 4);
  __syncthreads();
  STORE_X();
  __syncthreads();

  // ==== P11: Wb7 (buf1); sigma partials ====
  GLL_W(OFF_VIEW, 10240, 0);
  float nz = 0.f;
  if (tid < 256) nz = noise[p0 + tid];
  ACC_SET(b_blocks + 7 * 128);
  GEMM_X(LDS_W + 1 * 34816, 4);
  {
    f32x4 wo[4];
#pragma unroll
    for (int j = 0; j < 4; ++j) wo[j] = *(const f32x4*)(W_out + 64 * wc + 16 * j + 4 * h);
#pragma unroll
    for (int mi = 0; mi < 4; ++mi) {
      float s = 0.f;
#pragma unroll
      for (int j = 0; j < 4; ++j)
#pragma unroll
        for (int rr = 0; rr < 4; ++rr) s += fmaxf(acc[mi][j][rr], 0.f) * wo[j][rr];
      s += __shfl_xor(s, 16); s += __shfl_xor(s, 32);
      if (h == 0) *(float*)(lds + LDS_SP + ((64 * wr + 16 * mi + li) * 2 + wc) * 4) = s;
    }
  }
  __syncthreads();

  // ==== P12: enc_v@Wview (buf0, stride 80); stream app -> X; sigma combine ====
  GLL_W(OFF_VIEWC, 34816, 1);
  STREAM_COND(1);
  {
    bf16x8 envf[4][1];
#pragma unroll
    for (int mi = 0; mi < 4; ++mi) {
      float r0 = ray0[mi], r1 = ray1[mi], r2 = ray2[mi];
      float inv = 1.f / sqrtf(r0 * r0 + r1 * r1 + r2 * r2);
      r0 *= inv; r1 *= inv; r2 *= inv;
      u32 w[4];
#pragma unroll
      for (int e2 = 0; e2 < 4; ++e2) {
        int k0 = h * 8 + e2 * 2;
        w[e2] = pack2(enc_val3(r0, r1, r2, k0, 27), enc_val3(r0, r1, r2, k0 + 1, 27));
      }
      envf[mi][0] = mk8(w[0], w[1], w[2], w[3]);
    }
    ACC_ADD((const float*)(ws + OFF_BIASV));
    GEMM_E(LDS_W + 0 * 34816, 80, 1, envf);
  }
  float sig = 0.f;
  if (tid < 256) {
    const float* sp = (const float*)(lds + LDS_SP);
    float s = sp[2 * tid] + sp[2 * tid + 1] + b_out[0] + nz;
    sig = fmaxf(s, 0.f);
  }
  __syncthreads();

  // ==== P13: app@Wviewc (buf1); rgb ====
  GEMM_X(LDS_W + 1 * 34816, 4);
  {
#pragma unroll
    for (int mi = 0; mi < 4; ++mi) {
      float s0 = 0.f, s1 = 0.f, s2 = 0.f;
#pragma unroll
      for (int j = 0; j < 4; ++j)
#pragma unroll
        for (int rr = 0; rr < 4; ++rr) {
          float v = fmaxf(acc[mi][j][rr], 0.f);
          int n = 64 * wc + 16 * j + 4 * h + rr;
          s0 += v * W_rgb[n * 3 + 0];
          s1 += v * W_rgb[n * 3 + 1];
          s2 += v * W_rgb[n * 3 + 2];
        }
      s0 += __shfl_xor(s0, 16); s0 += __shfl_xor(s0, 32);
      s1 += __shfl_xor(s1, 16); s1 += __shfl_xor(s1, 32);
      s2 += __shfl_xor(s2, 16); s2 += __shfl_xor(s2, 32);
      if (h == 0) {
        float* rp = (float*)(lds + LDS_RP);
        int m_ = 64 * wr + 16 * mi + li;
        rp[(m_ * 2 + wc) * 3 + 0] = s0;
        rp[(m_ * 2 + wc) * 3 + 1] = s1;
        rp[(m_ * 2 + wc) * 3 + 2] = s2;
      }
    }
  }
  __syncthreads();
  if (tid < 256) {
    const float* rp = (const float*)(lds + LDS_RP);
    f32x4 o4;
    o4[0] = sig;
#pragma unroll
    for (int c = 0; c < 3; ++c) {
      float v = rp[(2 * tid) * 3 + c] + rp[(2 * tid + 1) * 3 + c] + b_rgb[c];
      o4[1 + c] = 1.f / (1.f + __expf(-v));
    }
    *(f32x4*)(out + (size_t)(p0 + tid) * 4) = o4;
  }
}

extern "C" void kernel_launch(void* const* d_in, const int* in_sizes, int n_in,
                              void* d_out, int out_size, void* d_ws, size_t ws_size,
                              hipStream_t stream) {
  const float* coords    = (const float*)d_in[0];
  const float* condition = (const float*)d_in[1];
  const float* ray_dir   = (const float*)d_in[2];
  const float* noise     = (const float*)d_in[3];
  const float* W_in      = (const float*)d_in[4];
  const float* b_in      = (const float*)d_in[5];
  const float* W_blocks  = (const float*)d_in[6];
  const float* b_blocks  = (const float*)d_in[7];
  const float* W_c       = (const float*)d_in[8];
  const float* b_c       = (const float*)d_in[9];
  const float* W_skip    = (const float*)d_in[10];
  const float* b_skip    = (const float*)d_in[11];
  const float* W_skipc   = (const float*)d_in[12];
  const float* b_skipc   = (const float*)d_in[13];
  const float* W_out     = (const float*)d_in[14];
  const float* b_out     = (const float*)d_in[15];
  const float* W_viewc   = (const float*)d_in[16];
  const float* b_viewc   = (const float*)d_in[17];
  const float* W_view    = (const float*)d_in[18];
  const float* b_view    = (const float*)d_in[19];
  const float* W_rgb     = (const float*)d_in[20];
  const float* b_rgb     = (const float*)d_in[21];
  char* ws = (char*)d_ws;
  float* out = (float*)d_out;

  prep_kernel<<<842, 256, 0, stream>>>(W_in, W_c, W_blocks, W_skip, W_skipc, W_view, W_viewc,
                                       b_in, b_c, b_skip, b_skipc, b_view, b_viewc, ws);
  nerf_main<<<1024, 512, LDS_TOTAL, stream>>>(coords, condition, ray_dir, noise,
                                              b_blocks, W_out, b_out, W_rgb, b_rgb, ws, out);
}

// Round 5
// 207.778 us; speedup vs baseline: 1.3513x; 1.1366x over previous
//
#include <hip/hip_runtime.h>
#include <hip/hip_bf16.h>

typedef unsigned int u32;
typedef unsigned short u16;

using bf16x8 = __attribute__((ext_vector_type(8))) short;
using f32x4  = __attribute__((ext_vector_type(4))) float;

// ---------------- workspace layout (bytes) ----------------
#define OFF_IN     0L        // Wt_in   [128][72]  bf16 = 18432
#define OFF_C      18432L    // Wt_c    [128][136] bf16 = 34816
#define OFF_B0     53248L    // Wt_b[8] [128][136] bf16 = 8*34816
#define OFF_SKIP   331776L   // Wt_skip [128][72]
#define OFF_SKIPC  350208L   // Wt_skipc[128][136]
#define OFF_VIEW   385024L   // Wt_view [128][40] = 10240
#define OFF_VIEWC  395264L   // Wt_viewc[128][136]
#define OFF_BIAS0  430080L   // f32[128] b_in+b_c
#define OFF_BIASSK 430592L   // f32[128] b_skip+b_skipc
#define OFF_BIASV  431104L   // f32[128] b_view+b_viewc

// ---------------- LDS layout (bytes): 72 KB -> 2 blocks/CU ----------------
#define LDS_X   0        // activations / cond halves [128][136] bf16, stride 272B = 34816
#define LDS_W   34816    // weight single buffer: 34816
#define LDS_SP  69632    // sigma partials [128][2] f32 = 1024
#define LDS_RP  70656    // rgb partials [128][2][3] f32 = 3072
#define LDS_TOTAL 73728

__device__ __forceinline__ u16 f2bf(float x) {
  union { float f; u32 u; } un; un.f = x;
  u32 u = un.u;
  return (u16)((u + 0x7fffu + ((u >> 16) & 1u)) >> 16);
}
__device__ __forceinline__ u32 pack2(float a, float b) {
  return (u32)f2bf(a) | ((u32)f2bf(b) << 16);
}
__device__ __forceinline__ float sel3(float a, float b, float c, int i) {
  return i == 0 ? a : (i == 1 ? b : c);
}
__device__ __forceinline__ float enc_val3(float a, float b, float c, int e, int kreal) {
  if (e >= kreal) return 0.f;
  if (e < 3) return sel3(a, b, c, e);
  int t = e - 3;
  int l = t / 6;
  int rem = t - l * 6;
  int pi = rem >= 3 ? rem - 3 : rem;
  float x = sel3(a, b, c, pi) * (float)(1 << l);
  return rem < 3 ? __sinf(x) : __cosf(x);
}
__device__ __forceinline__ bf16x8 mk8(u32 a, u32 b, u32 c, u32 d) {
  union { u32 u[4]; bf16x8 v; } t; t.u[0] = a; t.u[1] = b; t.u[2] = c; t.u[3] = d;
  return t.v;
}
// zero-VGPR weight staging: global -> LDS DMA (lds base wave-uniform, src per-lane)
__device__ __forceinline__ void gll16(const void* g, void* l) {
  __builtin_amdgcn_global_load_lds(
      (const __attribute__((address_space(1))) void*)g,
      (__attribute__((address_space(3))) void*)l, 16, 0, 0);
}

// ---------------- prep kernel (unchanged) ----------------
__global__ void prep_kernel(
    const float* __restrict__ Win, const float* __restrict__ Wc, const float* __restrict__ Wb,
    const float* __restrict__ Wskip, const float* __restrict__ Wskipc,
    const float* __restrict__ Wview, const float* __restrict__ Wviewc,
    const float* __restrict__ bin, const float* __restrict__ bc,
    const float* __restrict__ bskip, const float* __restrict__ bskipc,
    const float* __restrict__ bview, const float* __restrict__ bviewc,
    char* __restrict__ ws) {
  int i = blockIdx.x * 256 + threadIdx.x;
  if (i >= 215424) return;
  int r = i;
  const float* src; int kpad, kreal; long dstoff;
  if (r < 9216)                    { src = Win;    kpad = 72;  kreal = 63;  dstoff = OFF_IN; }
  else if ((r -= 9216) < 17408)    { src = Wc;     kpad = 136; kreal = 128; dstoff = OFF_C; }
  else if ((r -= 17408) < 139264)  { int b = r / 17408; r -= b * 17408;
                                     src = Wb + (long)b * 16384; kpad = 136; kreal = 128;
                                     dstoff = OFF_B0 + (long)b * 34816; }
  else if ((r -= 139264) < 9216)   { src = Wskip;  kpad = 72;  kreal = 63;  dstoff = OFF_SKIP; }
  else if ((r -= 9216) < 17408)    { src = Wskipc; kpad = 136; kreal = 128; dstoff = OFF_SKIPC; }
  else if ((r -= 17408) < 5120)    { src = Wview;  kpad = 40;  kreal = 27;  dstoff = OFF_VIEW; }
  else if ((r -= 5120) < 17408)    { src = Wviewc; kpad = 136; kreal = 128; dstoff = OFF_VIEWC; }
  else {
    r -= 17408;
    int which = r >> 7, n = r & 127;
    const float* A  = which == 0 ? bin : (which == 1 ? bskip : bview);
    const float* Bp = which == 0 ? bc  : (which == 1 ? bskipc : bviewc);
    long off = which == 0 ? OFF_BIAS0 : (which == 1 ? OFF_BIASSK : OFF_BIASV);
    *(float*)(ws + off + (long)n * 4) = A[n] + Bp[n];
    return;
  }
  int n = r / kpad, k = r - n * kpad;
  float v = (k < kreal) ? src[(long)k * 128 + n] : 0.f;
  *(u16*)(ws + dstoff + ((long)n * kpad + k) * 2) = f2bf(v);
}

// ---------------- staging: single-buffer global_load_lds ----------------
// 256 threads: 4 waves x 1024B per iteration = 4096B; max 9 iters for 34816
#define GLL_W(off, bytes)                                                      \
  do {                                                                         \
    _Pragma("unroll") for (int it_ = 0; it_ < 9; ++it_) {                      \
      int o_ = it_ * 4096 + wv * 1024;                                         \
      if (o_ < (bytes))                                                        \
        gll16(ws + (off) + o_ + lane * 16, lds + LDS_W + o_);                  \
    }                                                                          \
  } while (0)

// stream one 128-col half of condition (f32) -> packed bf16 LDS_X  (128 rows)
#define STREAM_COND(halfsel)                                                   \
  do {                                                                         \
    _Pragma("unroll") for (int c_ = 0; c_ < 4; ++c_) {                         \
      f32x4 v_[4];                                                             \
      _Pragma("unroll") for (int i2 = 0; i2 < 4; ++i2) {                       \
        int f4i = (4 * c_ + i2) * 256 + tid;                                   \
        int row = f4i >> 5, c4 = f4i & 31;                                     \
        v_[i2] = *(const f32x4*)(condition + (size_t)(p0 + row) * 256 +        \
                                 ((halfsel) * 32 + c4) * 4);                   \
      }                                                                        \
      _Pragma("unroll") for (int i2 = 0; i2 < 4; ++i2) {                       \
        int f4i = (4 * c_ + i2) * 256 + tid;                                   \
        int row = f4i >> 5, c4 = f4i & 31;                                     \
        uint2 t_; t_.x = pack2(v_[i2][0], v_[i2][1]);                          \
        t_.y = pack2(v_[i2][2], v_[i2][3]);                                    \
        *(uint2*)(lds + LDS_X + row * 272 + c4 * 8) = t_;                      \
      }                                                                        \
    }                                                                          \
  } while (0)

// recompute positional-encoding fragments from kept coords (12 regs)
#define ENC_COMPUTE(EF)                                                        \
  do {                                                                         \
    _Pragma("unroll") for (int mi_ = 0; mi_ < 4; ++mi_) {                      \
      _Pragma("unroll") for (int kt_ = 0; kt_ < 2; ++kt_) {                    \
        u32 w_[4];                                                             \
        _Pragma("unroll") for (int e2_ = 0; e2_ < 4; ++e2_) {                  \
          int k0_ = kt_ * 32 + h * 8 + e2_ * 2;                                \
          w_[e2_] = pack2(enc_val3(cx[mi_], cy[mi_], cz[mi_], k0_, 63),        \
                          enc_val3(cx[mi_], cy[mi_], cz[mi_], k0_ + 1, 63));   \
        }                                                                      \
        EF[mi_][kt_] = mk8(w_[0], w_[1], w_[2], w_[3]);                        \
      }                                                                        \
    }                                                                          \
  } while (0)

// ---------------- GEMM macros (swapped operands: D[lane&15] = point-row) ----------------
// acc[mi][j]: m = 64*wr+16*mi+li (lane li), n = 64*wc+16*j+4*h+rr (reg rr)
#define GEMM_X(WBASE, NKT)                                                     \
  do {                                                                         \
    _Pragma("unroll") for (int kt = 0; kt < (NKT); ++kt) {                     \
      bf16x8 xf[4];                                                            \
      _Pragma("unroll") for (int mi = 0; mi < 4; ++mi)                         \
        xf[mi] = *(const bf16x8*)(lds + LDS_X + (64*wr + 16*mi + li) * 272 + kt * 64 + h16); \
      _Pragma("unroll") for (int j = 0; j < 4; ++j) {                          \
        bf16x8 wf = *(const bf16x8*)(lds + (WBASE) + (64*wc + 16*j + li) * 272 + kt * 64 + h16); \
        _Pragma("unroll") for (int mi = 0; mi < 4; ++mi)                       \
          acc[mi][j] = __builtin_amdgcn_mfma_f32_16x16x32_bf16(wf, xf[mi], acc[mi][j], 0, 0, 0); \
      }                                                                        \
    }                                                                          \
  } while (0)

#define GEMM_E(WBASE, WSTR, NKT, EF)                                           \
  do {                                                                         \
    _Pragma("unroll") for (int kt = 0; kt < (NKT); ++kt) {                     \
      _Pragma("unroll") for (int j = 0; j < 4; ++j) {                          \
        bf16x8 wf = *(const bf16x8*)(lds + (WBASE) + (64*wc + 16*j + li) * (WSTR) + kt * 64 + h16); \
        _Pragma("unroll") for (int mi = 0; mi < 4; ++mi)                       \
          acc[mi][j] = __builtin_amdgcn_mfma_f32_16x16x32_bf16(wf, (EF)[mi][kt], acc[mi][j], 0, 0, 0); \
      }                                                                        \
    }                                                                          \
  } while (0)

#define ACC_SET(bptr)                                                          \
  do {                                                                         \
    _Pragma("unroll") for (int j = 0; j < 4; ++j) {                            \
      f32x4 b4_ = *(const f32x4*)((bptr) + 64*wc + 16*j + 4*h);                \
      _Pragma("unroll") for (int mi = 0; mi < 4; ++mi) acc[mi][j] = b4_;       \
    }                                                                          \
  } while (0)

#define ACC_ADD(bptr)                                                          \
  do {                                                                         \
    _Pragma("unroll") for (int j = 0; j < 4; ++j) {                            \
      f32x4 b4_ = *(const f32x4*)((bptr) + 64*wc + 16*j + 4*h);                \
      _Pragma("unroll") for (int mi = 0; mi < 4; ++mi) acc[mi][j] += b4_;      \
    }                                                                          \
  } while (0)

#define STORE_X()                                                              \
  do {                                                                         \
    _Pragma("unroll") for (int mi = 0; mi < 4; ++mi)                           \
    _Pragma("unroll") for (int j = 0; j < 4; ++j) {                            \
      f32x4 v_ = acc[mi][j];                                                   \
      uint2 t_;                                                                \
      t_.x = pack2(fmaxf(v_[0], 0.f), fmaxf(v_[1], 0.f));                      \
      t_.y = pack2(fmaxf(v_[2], 0.f), fmaxf(v_[3], 0.f));                      \
      *(uint2*)(lds + LDS_X + (64*wr + 16*mi + li) * 272 + (64*wc + 16*j + 4*h) * 2) = t_; \
    }                                                                          \
  } while (0)

// 256 threads (4 waves), 128 points/block, single W buffer, 72KB LDS:
// 2 blocks/CU (cross-block latency hiding) and a 256-VGPR budget (no spills).
__global__ void __launch_bounds__(256, 2) nerf_main(
    const float* __restrict__ coords, const float* __restrict__ condition,
    const float* __restrict__ ray_dir, const float* __restrict__ noise,
    const float* __restrict__ b_blocks, const float* __restrict__ W_out,
    const float* __restrict__ b_out, const float* __restrict__ W_rgb,
    const float* __restrict__ b_rgb, const char* __restrict__ ws,
    float* __restrict__ out) {
  extern __shared__ __align__(16) char lds[];
  const int tid = threadIdx.x;
  const int lane = tid & 63;
  const int wv = tid >> 6;          // 4 waves
  const int wr = wv >> 1, wc = wv & 1;
  const int li = lane & 15, h = lane >> 4;
  const int h16 = h * 16;
  const int p0 = blockIdx.x * 128;

  f32x4 acc[4][4];

  // ==== prologue: shape -> LDS_X, Win -> W, coords -> regs ====
  STREAM_COND(0);
  GLL_W(OFF_IN, 18432);
  float cx[4], cy[4], cz[4];
#pragma unroll
  for (int mi = 0; mi < 4; ++mi) {
    const float* cp = coords + (size_t)(p0 + 64 * wr + 16 * mi + li) * 3;
    cx[mi] = cp[0]; cy[mi] = cp[1]; cz[mi] = cp[2];
  }
  __syncthreads();

  // ==== P0: enc@Win ====
  {
    bf16x8 encf[4][2];
    ENC_COMPUTE(encf);
    ACC_SET((const float*)(ws + OFF_BIAS0));
    GEMM_E(LDS_W, 144, 2, encf);
  }
  __syncthreads();
  GLL_W(OFF_C, 34816);
  __syncthreads();

  // ==== P1: shape@Wc -> net0; store relu ====
  GEMM_X(LDS_W, 4);
  __syncthreads();
  GLL_W(OFF_B0 + 0L * 34816, 34816);
  STORE_X();
  __syncthreads();

  // ==== P2-P4: Wb0..Wb2 ====
#pragma unroll
  for (int idx = 0; idx < 3; ++idx) {
    ACC_SET(b_blocks + idx * 128);
    GEMM_X(LDS_W, 4);
    __syncthreads();
    GLL_W(OFF_B0 + (idx + 1) * 34816L, 34816);
    STORE_X();
    __syncthreads();
  }

  // ==== P5: Wb3 (no store; skip added onto net4 pre-relu) ====
  ACC_SET(b_blocks + 3 * 128);
  GEMM_X(LDS_W, 4);
  __syncthreads();
  GLL_W(OFF_SKIP, 18432);
  STREAM_COND(0);   // X free after P5's GEMM: rewrite shape
  __syncthreads();

  // ==== P6: enc@Wskip (no X read) ====
  {
    bf16x8 encf[4][2];
    ENC_COMPUTE(encf);
    ACC_ADD((const float*)(ws + OFF_BIASSK));
    GEMM_E(LDS_W, 144, 2, encf);
  }
  __syncthreads();
  GLL_W(OFF_SKIPC, 34816);
  __syncthreads();

  // ==== P7: shape@Wskipc; store relu(net4) ====
  GEMM_X(LDS_W, 4);
  __syncthreads();
  GLL_W(OFF_B0 + 4L * 34816, 34816);
  STORE_X();
  __syncthreads();

  // ==== P8-P10: Wb4..Wb6 ====
#pragma unroll
  for (int idx = 4; idx < 7; ++idx) {
    ACC_SET(b_blocks + idx * 128);
    GEMM_X(LDS_W, 4);
    __syncthreads();
    GLL_W(OFF_B0 + (idx + 1) * 34816L, 34816);
    STORE_X();
    __syncthreads();
  }

  // ray regs (needed at P12)
  float ray0[4], ray1[4], ray2[4];
#pragma unroll
  for (int mi = 0; mi < 4; ++mi) {
    size_t base = (size_t)(p0 + 64 * wr + 16 * mi + li) * 3;
    ray0[mi] = ray_dir[base]; ray1[mi] = ray_dir[base + 1]; ray2[mi] = ray_dir[base + 2];
  }
  float nz = 0.f;
  if (tid < 128) nz = noise[p0 + tid];

  // ==== P11: Wb7; sigma partials; then stage Wview + stream app ====
  ACC_SET(b_blocks + 7 * 128);
  GEMM_X(LDS_W, 4);
  {
    f32x4 wo[4];
#pragma unroll
    for (int j = 0; j < 4; ++j) wo[j] = *(const f32x4*)(W_out + 64 * wc + 16 * j + 4 * h);
#pragma unroll
    for (int mi = 0; mi < 4; ++mi) {
      float s = 0.f;
#pragma unroll
      for (int j = 0; j < 4; ++j)
#pragma unroll
        for (int rr = 0; rr < 4; ++rr) s += fmaxf(acc[mi][j][rr], 0.f) * wo[j][rr];
      s += __shfl_xor(s, 16); s += __shfl_xor(s, 32);
      if (h == 0) *(float*)(lds + LDS_SP + ((64 * wr + 16 * mi + li) * 2 + wc) * 4) = s;
    }
  }
  __syncthreads();
  GLL_W(OFF_VIEW, 10240);
  STREAM_COND(1);   // X free: app half
  __syncthreads();

  // ==== P12: enc_v@Wview; sigma combine ====
  {
    bf16x8 envf[4][1];
#pragma unroll
    for (int mi = 0; mi < 4; ++mi) {
      float r0 = ray0[mi], r1 = ray1[mi], r2 = ray2[mi];
      float inv = 1.f / sqrtf(r0 * r0 + r1 * r1 + r2 * r2);
      r0 *= inv; r1 *= inv; r2 *= inv;
      u32 w[4];
#pragma unroll
      for (int e2 = 0; e2 < 4; ++e2) {
        int k0 = h * 8 + e2 * 2;
        w[e2] = pack2(enc_val3(r0, r1, r2, k0, 27), enc_val3(r0, r1, r2, k0 + 1, 27));
      }
      envf[mi][0] = mk8(w[0], w[1], w[2], w[3]);
    }
    ACC_ADD((const float*)(ws + OFF_BIASV));
    GEMM_E(LDS_W, 80, 1, envf);
  }
  float sig = 0.f;
  if (tid < 128) {
    const float* sp = (const float*)(lds + LDS_SP);
    float s = sp[2 * tid] + sp[2 * tid + 1] + b_out[0] + nz;
    sig = fmaxf(s, 0.f);
  }
  __syncthreads();
  GLL_W(OFF_VIEWC, 34816);
  __syncthreads();

  // ==== P13: app@Wviewc; rgb ====
  GEMM_X(LDS_W, 4);
  {
#pragma unroll
    for (int mi = 0; mi < 4; ++mi) {
      float s0 = 0.f, s1 = 0.f, s2 = 0.f;
#pragma unroll
      for (int j = 0; j < 4; ++j)
#pragma unroll
        for (int rr = 0; rr < 4; ++rr) {
          float v = fmaxf(acc[mi][j][rr], 0.f);
          int n = 64 * wc + 16 * j + 4 * h + rr;
          s0 += v * W_rgb[n * 3 + 0];
          s1 += v * W_rgb[n * 3 + 1];
          s2 += v * W_rgb[n * 3 + 2];
        }
      s0 += __shfl_xor(s0, 16); s0 += __shfl_xor(s0, 32);
      s1 += __shfl_xor(s1, 16); s1 += __shfl_xor(s1, 32);
      s2 += __shfl_xor(s2, 16); s2 += __shfl_xor(s2, 32);
      if (h == 0) {
        float* rp = (float*)(lds + LDS_RP);
        int m_ = 64 * wr + 16 * mi + li;
        rp[(m_ * 2 + wc) * 3 + 0] = s0;
        rp[(m_ * 2 + wc) * 3 + 1] = s1;
        rp[(m_ * 2 + wc) * 3 + 2] = s2;
      }
    }
  }
  __syncthreads();
  if (tid < 128) {
    const float* rp = (const float*)(lds + LDS_RP);
    f32x4 o4;
    o4[0] = sig;
#pragma unroll
    for (int c = 0; c < 3; ++c) {
      float v = rp[(2 * tid) * 3 + c] + rp[(2 * tid + 1) * 3 + c] + b_rgb[c];
      o4[1 + c] = 1.f / (1.f + __expf(-v));
    }
    *(f32x4*)(out + (size_t)(p0 + tid) * 4) = o4;
  }
}

extern "C" void kernel_launch(void* const* d_in, const int* in_sizes, int n_in,
                              void* d_out, int out_size, void* d_ws, size_t ws_size,
                              hipStream_t stream) {
  const float* coords    = (const float*)d_in[0];
  const float* condition = (const float*)d_in[1];
  const float* ray_dir   = (const float*)d_in[2];
  const float* noise     = (const float*)d_in[3];
  const float* W_in      = (const float*)d_in[4];
  const float* b_in      = (const float*)d_in[5];
  const float* W_blocks  = (const float*)d_in[6];
  const float* b_blocks  = (const float*)d_in[7];
  const float* W_c       = (const float*)d_in[8];
  const float* b_c       = (const float*)d_in[9];
  const float* W_skip    = (const float*)d_in[10];
  const float* b_skip    = (const float*)d_in[11];
  const float* W_skipc   = (const float*)d_in[12];
  const float* b_skipc   = (const float*)d_in[13];
  const float* W_out     = (const float*)d_in[14];
  const float* b_out     = (const float*)d_in[15];
  const float* W_viewc   = (const float*)d_in[16];
  const float* b_viewc   = (const float*)d_in[17];
  const float* W_view    = (const float*)d_in[18];
  const float* b_view    = (const float*)d_in[19];
  const float* W_rgb     = (const float*)d_in[20];
  const float* b_rgb     = (const float*)d_in[21];
  char* ws = (char*)d_ws;
  float* out = (float*)d_out;

  prep_kernel<<<842, 256, 0, stream>>>(W_in, W_c, W_blocks, W_skip, W_skipc, W_view, W_viewc,
                                       b_in, b_c, b_skip, b_skipc, b_view, b_viewc, ws);
  nerf_main<<<2048, 256, LDS_TOTAL, stream>>>(coords, condition, ray_dir, noise,
                                              b_blocks, W_out, b_out, W_rgb, b_rgb, ws, out);
}